// Round 3
// baseline (303.896 us; speedup 1.0000x reference)
//
#include <hip/hip_runtime.h>

// Problem constants (B=32, T=4096, D=256, A=128, window=64)
#define TT 4096
#define DD 256
#define AA 128
#define WIN 64

typedef short bf16x8 __attribute__((ext_vector_type(8)));
typedef float f32x4 __attribute__((ext_vector_type(4)));
typedef unsigned int u32x4 __attribute__((ext_vector_type(4)));

__device__ __forceinline__ unsigned short f2bf(float f) {
    unsigned int u = __builtin_bit_cast(unsigned int, f);
    u += 0x7FFFu + ((u >> 16) & 1u);   // RTNE
    return (unsigned short)(u >> 16);
}

// packed f32x2 -> bf16x2 (RTNE), element 0 = lo
__device__ __forceinline__ unsigned int cvt_pk_bf16(float lo, float hi) {
    unsigned int r;
    asm("v_cvt_pk_bf16_f32 %0, %1, %2" : "=v"(r) : "v"(lo), "v"(hi));
    return r;
}

template <int W> __device__ __forceinline__ void waitcnt_vm() {
    if constexpr (W == 16)      asm volatile("s_waitcnt vmcnt(16)" ::: "memory");
    else if constexpr (W == 8)  asm volatile("s_waitcnt vmcnt(8)"  ::: "memory");
    else                        asm volatile("s_waitcnt vmcnt(0)"  ::: "memory");
    __builtin_amdgcn_sched_barrier(0);
}

// ---------------- prep: Wp fp32 -> bf16 (64 KiB, L2-resident) ----------------
__global__ __launch_bounds__(256) void prep_wp(const float* __restrict__ Wp,
                                               unsigned short* __restrict__ wpb) {
    int i = blockIdx.x * 256 + threadIdx.x;   // 32768 total
    wpb[i] = f2bf(Wp[i]);
}

// ---------------- gate: g = sigmoid(Wg . tanh(x Wp^T + bp)) ------------------
// v3: T3+T4. Persistent 256-block kernel (1 block/CU), 512 rows/block as 16
// subtiles of 32 rows. 3-buffer LDS pipeline staged via global_load_lds
// (dwordx4, XOR-swizzled source, linear dest), counted s_waitcnt vmcnt(16)
// + RAW s_barrier -- 2 subtiles (16 loads/wave) stay in flight across every
// barrier; vmcnt never drains to 0 in the main loop. Per-subtile psum is
// barrier-free (private slab per wave); one reduction at block end.
#define SROWS 32
#define BROWS 512
#define NSUB  (BROWS / SROWS)   // 16

__global__ __launch_bounds__(256, 1) void gate_kernel(
        const float* __restrict__ x, const unsigned short* __restrict__ wpb,
        const float* __restrict__ bp, const float* __restrict__ Wg,
        float* __restrict__ g) {
    __shared__ __align__(16) float xs[3][SROWS * DD];   // 3 x 32 KiB fp32
    __shared__ float psum[4][BROWS];                    // 8 KiB
    const int tid  = threadIdx.x;
    const int lane = tid & 63;
    const int wave = tid >> 6;
    const int quad = lane >> 4;
    const int nrow = lane & 15;
    const int sw   = nrow & 7;          // row&7 == nrow&7 (mt*16 ≡ 0 mod 8)
    const long row0 = (long)blockIdx.x * BROWS;
    const float* xbase = x + row0 * DD;

    // B fragments: wave covers n in [wave*32, wave*32+32)
    bf16x8 bfrag[2][8];
    float bpv[2], wgv[2];
#pragma unroll
    for (int nt = 0; nt < 2; ++nt) {
        int n = wave * 32 + nt * 16 + nrow;
        bpv[nt] = bp[n];
        wgv[nt] = Wg[n];
#pragma unroll
        for (int k0 = 0; k0 < 8; ++k0)
            bfrag[nt][k0] = *reinterpret_cast<const bf16x8*>(
                wpb + n * DD + k0 * 32 + quad * 8);
    }

    // stage subtile s into buffer nb: 8 global_load_lds dwordx4 per wave.
    // LDS dest linear (row r, granule lane); global source granule lane^(r&7),
    // so a read of granule gidx comes from slot gidx^(r&7).
    auto stage = [&](int nb, int s) {
        const float* src = xbase + (long)s * SROWS * DD;
#pragma unroll
        for (int j = 0; j < 8; ++j) {
            int r = wave * 8 + j;
            const float* gp = src + r * DD + ((lane ^ (r & 7)) << 2);
            __builtin_amdgcn_global_load_lds(
                (const __attribute__((address_space(1))) void*)gp,
                (__attribute__((address_space(3))) void*)&xs[nb][r * DD],
                16, 0, 0);
        }
    };

    // compute subtile s from buffer buf: ds_read + cvt + MFMA + epilogue,
    // psum write is race-free (per-wave slab), no barrier inside.
    auto compute = [&](const float* buf, int s) {
        f32x4 acc[2][2];
#pragma unroll
        for (int mt = 0; mt < 2; ++mt)
#pragma unroll
            for (int nt = 0; nt < 2; ++nt)
                acc[mt][nt] = (f32x4){0.f, 0.f, 0.f, 0.f};

#pragma unroll
        for (int k0 = 0; k0 < 8; ++k0) {
#pragma unroll
            for (int mt = 0; mt < 2; ++mt) {
                const float* rowp = buf + (mt * 16 + nrow) * DD;
                const int gidx = quad * 2 + k0 * 8;
                float4 f0 = *reinterpret_cast<const float4*>(rowp + (((gidx)     ^ sw) << 2));
                float4 f1 = *reinterpret_cast<const float4*>(rowp + (((gidx + 1) ^ sw) << 2));
                u32x4 w;
                w.x = cvt_pk_bf16(f0.x, f0.y);
                w.y = cvt_pk_bf16(f0.z, f0.w);
                w.z = cvt_pk_bf16(f1.x, f1.y);
                w.w = cvt_pk_bf16(f1.z, f1.w);
                bf16x8 af = __builtin_bit_cast(bf16x8, w);
                acc[mt][0] = __builtin_amdgcn_mfma_f32_16x16x32_bf16(af, bfrag[0][k0], acc[mt][0], 0, 0, 0);
                acc[mt][1] = __builtin_amdgcn_mfma_f32_16x16x32_bf16(af, bfrag[1][k0], acc[mt][1], 0, 0, 0);
            }
        }

        // epilogue: tanh -> *Wg -> partial row sums (this wave's 32 n-cols)
        float p[2][4];
#pragma unroll
        for (int mt = 0; mt < 2; ++mt)
#pragma unroll
            for (int r = 0; r < 4; ++r) p[mt][r] = 0.f;
#pragma unroll
        for (int nt = 0; nt < 2; ++nt) {
#pragma unroll
            for (int mt = 0; mt < 2; ++mt) {
#pragma unroll
                for (int r = 0; r < 4; ++r) {
                    float pre = acc[mt][nt][r] + bpv[nt];
                    float e  = __expf(2.0f * pre);
                    float th = 1.0f - 2.0f * __builtin_amdgcn_rcpf(e + 1.0f);
                    p[mt][r] += th * wgv[nt];
                }
            }
        }
        // reduce over the 16 nrow lanes (lane bits 0..3)
#pragma unroll
        for (int off = 1; off <= 8; off <<= 1)
#pragma unroll
            for (int mt = 0; mt < 2; ++mt)
#pragma unroll
                for (int r = 0; r < 4; ++r)
                    p[mt][r] += __shfl_xor(p[mt][r], off, 64);
        if (nrow == 0) {
#pragma unroll
            for (int mt = 0; mt < 2; ++mt)
#pragma unroll
                for (int r = 0; r < 4; ++r)
                    psum[wave][s * 32 + mt * 16 + quad * 4 + r] = p[mt][r];
        }
    };

    // prologue: 3 subtiles in flight (24 loads/wave)
    stage(0, 0);
    stage(1, 1);
    stage(2, 2);

    int bi = 0;
    for (int s = 0; s < NSUB; ++s) {
        // wait for stage s: leave stages s+1, s+2 (16 loads) in flight
        if (s < NSUB - 2)       waitcnt_vm<16>();
        else if (s == NSUB - 2) waitcnt_vm<8>();
        else                    waitcnt_vm<0>();
        __builtin_amdgcn_s_barrier();           // all waves' stage-s complete
        __builtin_amdgcn_sched_barrier(0);

        compute(xs[bi], s);

        __builtin_amdgcn_sched_barrier(0);
        asm volatile("s_waitcnt lgkmcnt(0)" ::: "memory");
        __builtin_amdgcn_sched_barrier(0);
        __builtin_amdgcn_s_barrier();           // all waves done reading buf bi
        __builtin_amdgcn_sched_barrier(0);

        if (s < NSUB - 3) stage(bi, s + 3);     // reuse the buffer just drained
        bi = (bi == 2) ? 0 : bi + 1;
    }

    // final reduction: psum already fenced by last lgkmcnt(0)+barrier
    for (int i = tid; i < BROWS; i += 256) {
        float ssum = psum[0][i] + psum[1][i] + psum[2][i] + psum[3][i];
        g[row0 + i] = __builtin_amdgcn_rcpf(1.0f + __expf(-ssum));
    }
}

// ---------------- stream: windowed sum of g*x over win=64, / windowed g-sum --
// float2-vectorized. Block = 256 thr = 2 groups of 128; each group owns one
// (b, chunk), lane owns 2 d-columns. S += g[t]x[t] - g[t-64]x[t-64]; the
// subtrahend re-read is L2-warm. den fused as scalar recurrence on staged g.
#define TC 128
#define NCHUNK (TT / TC)   // 32

__global__ __launch_bounds__(256) void stream_kernel(
        const float* __restrict__ x, const float* __restrict__ g,
        float* __restrict__ out) {
    __shared__ float gbuf[2][TC + WIN];
    const int grp  = threadIdx.x >> 7;           // 0..1
    const int d2   = threadIdx.x & 127;          // float2 column index
    const int pair = blockIdx.x * 2 + grp;       // (b, chunk) id, 0..1023
    const int b     = pair >> 5;                 // NCHUNK = 32
    const int chunk = pair & (NCHUNK - 1);
    const int t0    = chunk * TC;
    const float2* xb2 = reinterpret_cast<const float2*>(x + (size_t)b * TT * DD);
    const float*  gb  = g + (size_t)b * TT;
    float2* ob2 = reinterpret_cast<float2*>(out + (size_t)b * TT * DD);

    // stage g[t0-64 .. t0+TC-1], zero-padded below 0
    for (int i = d2; i < TC + WIN; i += 128) {
        int s = t0 - WIN + i;
        gbuf[grp][i] = (s >= 0) ? gb[s] : 0.f;
    }
    __syncthreads();

    // halo init over [t0-64, t0-1] (g=0 padding kills clamped loads)
    float2 S = {0.f, 0.f};
    float Sg = 0.f;
#pragma unroll 16
    for (int i = 0; i < WIN; ++i) {
        int s  = t0 - WIN + i;
        int sc = s < 0 ? 0 : s;
        float gv = gbuf[grp][i];
        float2 xv = xb2[(size_t)sc * (DD / 2) + d2];
        S.x += gv * xv.x;
        S.y += gv * xv.y;
        Sg  += gv;
    }

#pragma unroll 8
    for (int tt = 0; tt < TC; ++tt) {
        int t   = t0 + tt;
        int ts  = t - WIN;
        int tsc = ts < 0 ? 0 : ts;
        float gnew = gbuf[grp][WIN + tt];
        float gold = gbuf[grp][tt];
        float2 xn = xb2[(size_t)t   * (DD / 2) + d2];
        float2 xo = xb2[(size_t)tsc * (DD / 2) + d2];
        S.x += gnew * xn.x - gold * xo.x;
        S.y += gnew * xn.y - gold * xo.y;
        Sg  += gnew - gold;
        float r = __builtin_amdgcn_rcpf(Sg);
        float2 o; o.x = S.x * r; o.y = S.y * r;
        ob2[(size_t)t * (DD / 2) + d2] = o;
    }
}

extern "C" void kernel_launch(void* const* d_in, const int* in_sizes, int n_in,
                              void* d_out, int out_size, void* d_ws, size_t ws_size,
                              hipStream_t stream) {
    const float* x  = (const float*)d_in[0];
    const float* Wp = (const float*)d_in[1];
    const float* bp = (const float*)d_in[2];
    const float* Wg = (const float*)d_in[3];
    float* out = (float*)d_out;

    // ws layout: [0,64K) Wp bf16 | [64K, 64K+512K) g
    unsigned short* wpb = (unsigned short*)d_ws;
    float* g = (float*)((char*)d_ws + 65536);

    prep_wp<<<AA * DD / 256, 256, 0, stream>>>(Wp, wpb);
    gate_kernel<<<32 * TT / BROWS, 256, 0, stream>>>(x, wpb, bp, Wg, g);
    stream_kernel<<<32 * NCHUNK / 2, 256, 0, stream>>>(x, g, out);
}

// Round 4
// 266.264 us; speedup vs baseline: 1.1413x; 1.1413x over previous
//
#include <hip/hip_runtime.h>

// Problem constants (B=32, T=4096, D=256, A=128, window=64)
#define TT 4096
#define DD 256
#define AA 128
#define WIN 64

typedef short bf16x8 __attribute__((ext_vector_type(8)));
typedef float f32x4 __attribute__((ext_vector_type(4)));
typedef unsigned int u32x4 __attribute__((ext_vector_type(4)));

__device__ __forceinline__ unsigned short f2bf(float f) {
    unsigned int u = __builtin_bit_cast(unsigned int, f);
    u += 0x7FFFu + ((u >> 16) & 1u);   // RTNE
    return (unsigned short)(u >> 16);
}

// packed f32x2 -> bf16x2 (RTNE), element 0 = lo
__device__ __forceinline__ unsigned int cvt_pk_bf16(float lo, float hi) {
    unsigned int r;
    asm("v_cvt_pk_bf16_f32 %0, %1, %2" : "=v"(r) : "v"(lo), "v"(hi));
    return r;
}

// ---------------- prep: Wp fp32 -> bf16 (64 KiB, L2-resident) ----------------
__global__ __launch_bounds__(256) void prep_wp(const float* __restrict__ Wp,
                                               unsigned short* __restrict__ wpb) {
    int i = blockIdx.x * 256 + threadIdx.x;   // 32768 total
    wpb[i] = f2bf(Wp[i]);
}

// ---------------- fused: gate + windowed stream, x read ONCE -----------------
// g[t] is pointwise in t, so gate and stream fuse. Block owns TC=512 rows +
// 64-row halo = 18 subtiles of 32 rows. 4-deep LDS ring of fp32 x-subtiles
// (XOR-swizzled source, linear dest via global_load_lds dwordx4). Per subtile:
// MFMA gate -> g into LDS ring -> windowed recurrence vs ring buffers u (new)
// and u-2 (old, exactly t-64). x: HBM once. out: HBM once. g: never global.
#define SROWS 32
#define TC    512
#define NU    ((TC + WIN) / SROWS)   // 18 subtiles incl. 2 halo
#define NCHK  (TT / TC)              // 8 chunks per batch row

__global__ __launch_bounds__(256, 1) void fused_kernel(
        const float* __restrict__ x, const unsigned short* __restrict__ wpb,
        const float* __restrict__ bp, const float* __restrict__ Wg,
        float* __restrict__ out) {
    __shared__ __align__(16) float xs[4][SROWS * DD];   // 128 KiB ring
    __shared__ float gbuf[4][SROWS];                    // g ring (tracks xs)
    __shared__ float psum[4][SROWS];                    // per-wave gate partials
    const int tid  = threadIdx.x;
    const int lane = tid & 63;
    const int wave = tid >> 6;
    const int quad = lane >> 4;
    const int nrow = lane & 15;
    const int sw   = nrow & 7;          // row&7 == nrow&7 (mt*16 ≡ 0 mod 8)
    const int b     = blockIdx.x >> 3;          // NCHK = 8
    const int chunk = blockIdx.x & (NCHK - 1);
    const long t0   = (long)chunk * TC;
    const float* xb = x   + (size_t)b * TT * DD;
    float*       ob = out + (size_t)b * TT * DD;

    // B fragments: wave covers n in [wave*32, wave*32+32)
    bf16x8 bfrag[2][8];
    float bpv[2], wgv[2];
#pragma unroll
    for (int nt = 0; nt < 2; ++nt) {
        int n = wave * 32 + nt * 16 + nrow;
        bpv[nt] = bp[n];
        wgv[nt] = Wg[n];
#pragma unroll
        for (int k0 = 0; k0 < 8; ++k0)
            bfrag[nt][k0] = *reinterpret_cast<const bf16x8*>(
                wpb + n * DD + k0 * 32 + quad * 8);
    }

    // stage subtile u (rows t0-64+32u .. +31, clamped at 0) into ring slot u&3.
    // LDS dest linear (row r, granule lane); global source granule lane^(r&7),
    // so a read of granule gidx comes from slot gidx^(r&7).
    auto stage = [&](int u) {
        const int nb = u & 3;
        const long r0 = t0 - WIN + (long)u * SROWS;
#pragma unroll
        for (int j = 0; j < 8; ++j) {
            int r = wave * 8 + j;
            long row = r0 + r;
            row = row < 0 ? 0 : row;          // t0=0 halo clamp (g=0 kills it)
            const float* gp = xb + row * DD + ((lane ^ (r & 7)) << 2);
            __builtin_amdgcn_global_load_lds(
                (const __attribute__((address_space(1))) void*)gp,
                (__attribute__((address_space(3))) void*)&xs[nb][r * DD],
                16, 0, 0);
        }
    };

    float S = 0.f, Sg = 0.f;    // windowed recurrence state (thread owns col d=tid)

    stage(0);
    asm volatile("s_waitcnt vmcnt(0)" ::: "memory");
    __builtin_amdgcn_sched_barrier(0);
    __builtin_amdgcn_s_barrier();
    __builtin_amdgcn_sched_barrier(0);

    for (int u = 0; u < NU; ++u) {
        if (u + 1 < NU) stage(u + 1);        // prefetch, in flight all body

        // ---- gate MFMA on xs[u&3] ----
        const float* buf = xs[u & 3];
        f32x4 acc[2][2];
#pragma unroll
        for (int mt = 0; mt < 2; ++mt)
#pragma unroll
            for (int nt = 0; nt < 2; ++nt)
                acc[mt][nt] = (f32x4){0.f, 0.f, 0.f, 0.f};
#pragma unroll
        for (int k0 = 0; k0 < 8; ++k0) {
#pragma unroll
            for (int mt = 0; mt < 2; ++mt) {
                const float* rowp = buf + (mt * 16 + nrow) * DD;
                const int gidx = quad * 2 + k0 * 8;
                float4 f0 = *reinterpret_cast<const float4*>(rowp + (((gidx)     ^ sw) << 2));
                float4 f1 = *reinterpret_cast<const float4*>(rowp + (((gidx + 1) ^ sw) << 2));
                u32x4 w;
                w.x = cvt_pk_bf16(f0.x, f0.y);
                w.y = cvt_pk_bf16(f0.z, f0.w);
                w.z = cvt_pk_bf16(f1.x, f1.y);
                w.w = cvt_pk_bf16(f1.z, f1.w);
                bf16x8 af = __builtin_bit_cast(bf16x8, w);
                acc[mt][0] = __builtin_amdgcn_mfma_f32_16x16x32_bf16(af, bfrag[0][k0], acc[mt][0], 0, 0, 0);
                acc[mt][1] = __builtin_amdgcn_mfma_f32_16x16x32_bf16(af, bfrag[1][k0], acc[mt][1], 0, 0, 0);
            }
        }
        // epilogue: tanh -> *Wg -> partial row sums (this wave's 32 n-cols)
        float p[2][4];
#pragma unroll
        for (int mt = 0; mt < 2; ++mt)
#pragma unroll
            for (int r = 0; r < 4; ++r) p[mt][r] = 0.f;
#pragma unroll
        for (int nt = 0; nt < 2; ++nt) {
#pragma unroll
            for (int mt = 0; mt < 2; ++mt) {
#pragma unroll
                for (int r = 0; r < 4; ++r) {
                    float pre = acc[mt][nt][r] + bpv[nt];
                    float e  = __expf(2.0f * pre);
                    float th = 1.0f - 2.0f * __builtin_amdgcn_rcpf(e + 1.0f);
                    p[mt][r] += th * wgv[nt];
                }
            }
        }
#pragma unroll
        for (int off = 1; off <= 8; off <<= 1)
#pragma unroll
            for (int mt = 0; mt < 2; ++mt)
#pragma unroll
                for (int r = 0; r < 4; ++r)
                    p[mt][r] += __shfl_xor(p[mt][r], off, 64);
        if (nrow == 0) {
#pragma unroll
            for (int mt = 0; mt < 2; ++mt)
#pragma unroll
                for (int r = 0; r < 4; ++r)
                    psum[wave][mt * 16 + quad * 4 + r] = p[mt][r];
        }

        asm volatile("s_waitcnt lgkmcnt(0)" ::: "memory");
        __builtin_amdgcn_sched_barrier(0);
        __builtin_amdgcn_s_barrier();            // psum visible
        __builtin_amdgcn_sched_barrier(0);

        // ---- finalize g[u] into the ring ----
        if (tid < SROWS) {
            float ssum = psum[0][tid] + psum[1][tid] + psum[2][tid] + psum[3][tid];
            float gg = __builtin_amdgcn_rcpf(1.0f + __expf(-ssum));
            long row = t0 - WIN + (long)u * SROWS + tid;
            gbuf[u & 3][tid] = (row < 0) ? 0.f : gg;
        }
        asm volatile("s_waitcnt lgkmcnt(0)" ::: "memory");
        __builtin_amdgcn_sched_barrier(0);
        __builtin_amdgcn_s_barrier();            // gbuf visible
        __builtin_amdgcn_sched_barrier(0);

        // ---- windowed recurrence: thread owns column d = tid ----
        if (u >= 2) {
            const int v  = u - 2;
            const int bn = u & 3, bo = v & 3;
            const float* fn = xs[bn];
            const float* fo = xs[bo];
            const long tbase = t0 + (long)v * SROWS;
#pragma unroll 8
            for (int tt = 0; tt < SROWS; ++tt) {
                int off = tt * DD + ((((tid >> 2) ^ (tt & 7)) << 2) | (tid & 3));
                float gnew = gbuf[bn][tt];
                float gold = gbuf[bo][tt];
                S  += gnew * fn[off] - gold * fo[off];
                Sg += gnew - gold;
                ob[(tbase + tt) * DD + tid] = S * __builtin_amdgcn_rcpf(Sg);
            }
        } else {
            // halo accumulation: build S,Sg over [t0-64, t0)
            const int bn = u & 3;
            const float* fn = xs[bn];
#pragma unroll 8
            for (int tt = 0; tt < SROWS; ++tt) {
                int off = tt * DD + ((((tid >> 2) ^ (tt & 7)) << 2) | (tid & 3));
                float gnew = gbuf[bn][tt];
                S  += gnew * fn[off];
                Sg += gnew;
            }
        }

        asm volatile("s_waitcnt vmcnt(0)" ::: "memory");   // drain prefetch+stores
        __builtin_amdgcn_sched_barrier(0);
        __builtin_amdgcn_s_barrier();            // ring slots free for next stage
        __builtin_amdgcn_sched_barrier(0);
    }
}

extern "C" void kernel_launch(void* const* d_in, const int* in_sizes, int n_in,
                              void* d_out, int out_size, void* d_ws, size_t ws_size,
                              hipStream_t stream) {
    const float* x  = (const float*)d_in[0];
    const float* Wp = (const float*)d_in[1];
    const float* bp = (const float*)d_in[2];
    const float* Wg = (const float*)d_in[3];
    float* out = (float*)d_out;

    // ws layout: [0,64K) Wp bf16
    unsigned short* wpb = (unsigned short*)d_ws;

    prep_wp<<<AA * DD / 256, 256, 0, stream>>>(Wp, wpb);
    fused_kernel<<<32 * NCHK, 256, 0, stream>>>(x, wpb, bp, Wg, out);
}